// Round 1
// baseline (23839.441 us; speedup 1.0000x reference)
//
#include <hip/hip_runtime.h>
#include <math.h>

#define Bsz 512
#define HID 196
#define REC 488
#define NC  35
#define TT  120
#define G3  (3*REC)   // 1464

#define KT  16
#define LDP 36        // padded LDS row stride (multiple of 4 floats, conflict-free)

struct TileSmem {
  float A [KT][LDP];
  float Wr[KT][LDP];
  float Wz[KT][LDP];
  float Wn[KT][LDP];
};

union PipeSmem {
  TileSmem t;
  struct { float xs[REC]; float hs[NC]; float rh[NC]; } c;
};

__device__ __forceinline__ float sigmoidf_(float x) { return 1.0f / (1.0f + __expf(-x)); }

// ---- phase A: z = bn(X @ W.T + bias, g, beta) ----
__global__ void dense_bn_kernel(const float* __restrict__ X, const float* __restrict__ W,
                                const float* __restrict__ bias, const float* __restrict__ g,
                                const float* __restrict__ beta, float* __restrict__ Y) {
  __shared__ float xs[HID];
  int b = blockIdx.x;
  for (int k = threadIdx.x; k < HID; k += blockDim.x) xs[k] = X[(size_t)b*HID + k];
  __syncthreads();
  int j = threadIdx.x;
  if (j < HID) {
    const float4* wr = (const float4*)(W + (size_t)j*HID);
    float acc = 0.f;
    #pragma unroll 7
    for (int k4 = 0; k4 < HID/4; ++k4) {
      float4 w4 = wr[k4];
      acc += xs[4*k4+0]*w4.x + xs[4*k4+1]*w4.y + xs[4*k4+2]*w4.z + xs[4*k4+3]*w4.w;
    }
    float v = (acc + bias[j]) * 0.9995003746f;   // 1/sqrt(1+1e-3)
    Y[(size_t)b*HID + j] = g[j]*v + beta[j];
  }
}

// ---- phase A: xg0 = z @ Wih0.T + bih0   (constant over all T) ----
__global__ void xg0_kernel(const float* __restrict__ Z, const float* __restrict__ Wih,
                           const float* __restrict__ bih, float* __restrict__ XG) {
  __shared__ float zs[HID];
  int b = blockIdx.x;
  for (int k = threadIdx.x; k < HID; k += blockDim.x) zs[k] = Z[(size_t)b*HID + k];
  __syncthreads();
  for (int c = threadIdx.x; c < G3; c += blockDim.x) {
    const float4* wr = (const float4*)(Wih + (size_t)c*HID);
    float acc = 0.f;
    for (int k4 = 0; k4 < HID/4; ++k4) {
      float4 w4 = wr[k4];
      acc += zs[4*k4+0]*w4.x + zs[4*k4+1]*w4.y + zs[4*k4+2]*w4.z + zs[4*k4+3]*w4.w;
    }
    XG[(size_t)b*G3 + c] = acc + bih[c];
  }
}

// ---- LDS tile loaders (transposed: [k][row]) ----
__device__ __forceinline__ void load_tileA(float (&dst)[KT][LDP], const float* __restrict__ A,
                                           int b0, int kk) {
  int tid  = threadIdx.x;
  int row  = tid >> 1;
  int kloc = (tid & 1) * 8;
  int kb   = kk + kloc;
  const float* src = A + (size_t)(b0 + row) * REC;
  float4 v0 = make_float4(0.f,0.f,0.f,0.f), v1 = v0;
  if (kb     < REC) v0 = *(const float4*)(src + kb);
  if (kb + 4 < REC) v1 = *(const float4*)(src + kb + 4);
  dst[kloc+0][row]=v0.x; dst[kloc+1][row]=v0.y; dst[kloc+2][row]=v0.z; dst[kloc+3][row]=v0.w;
  dst[kloc+4][row]=v1.x; dst[kloc+5][row]=v1.y; dst[kloc+6][row]=v1.z; dst[kloc+7][row]=v1.w;
}

__device__ __forceinline__ void load_tileW(float (&dst)[KT][LDP], const float* __restrict__ W,
                                           int rowbase, int cvalid, int kk) {
  int tid  = threadIdx.x;
  int row  = tid >> 1;
  int kloc = (tid & 1) * 8;
  int kb   = kk + kloc;
  float4 v0 = make_float4(0.f,0.f,0.f,0.f), v1 = v0;
  if (row < cvalid) {
    const float* src = W + (size_t)(rowbase + row) * REC;
    if (kb     < REC) v0 = *(const float4*)(src + kb);
    if (kb + 4 < REC) v1 = *(const float4*)(src + kb + 4);
  }
  dst[kloc+0][row]=v0.x; dst[kloc+1][row]=v0.y; dst[kloc+2][row]=v0.z; dst[kloc+3][row]=v0.w;
  dst[kloc+4][row]=v1.x; dst[kloc+5][row]=v1.y; dst[kloc+6][row]=v1.z; dst[kloc+7][row]=v1.w;
}

__device__ __forceinline__ void mma_tiles(const TileSmem& S, float (&ar)[4][4],
                                          float (&az)[4][4], float (&an)[4][4]) {
  int tx = threadIdx.x & 7;
  int ty = threadIdx.x >> 3;
  #pragma unroll
  for (int k = 0; k < KT; ++k) {
    float a[4], wr[4], wz[4], wn[4];
    #pragma unroll
    for (int i = 0; i < 4; ++i) a[i] = S.A[k][ty*4 + i];
    #pragma unroll
    for (int j = 0; j < 4; ++j) {
      wr[j] = S.Wr[k][tx*4 + j];
      wz[j] = S.Wz[k][tx*4 + j];
      wn[j] = S.Wn[k][tx*4 + j];
    }
    #pragma unroll
    for (int i = 0; i < 4; ++i)
      #pragma unroll
      for (int j = 0; j < 4; ++j) {
        ar[i][j] = fmaf(a[i], wr[j], ar[i][j]);
        az[i][j] = fmaf(a[i], wz[j], az[i][j]);
        an[i][j] = fmaf(a[i], wn[j], an[i][j]);
      }
  }
}

// accumulate one A[32rows]x W(3 gates, 32 cols).T segment over K=REC
__device__ __forceinline__ void gemm_segment(TileSmem& S, const float* __restrict__ A,
                                             const float* __restrict__ W,
                                             int b0, int c0, int cvalid,
                                             float (&ar)[4][4], float (&az)[4][4], float (&an)[4][4]) {
  for (int kk = 0; kk < REC; kk += KT) {
    __syncthreads();
    load_tileA(S.A,  A, b0, kk);
    load_tileW(S.Wr, W, 0*REC + c0, cvalid, kk);
    load_tileW(S.Wz, W, 1*REC + c0, cvalid, kk);
    load_tileW(S.Wn, W, 2*REC + c0, cvalid, kk);
    __syncthreads();
    mma_tiles(S, ar, az, an);
  }
}

// ---- fused pipelined step kernel: G0(t=s) || G1(t=s-1) || cell(t=s-2) ----
__global__ __launch_bounds__(64)
void pipe_kernel(const float* __restrict__ xg0,
                 float* __restrict__ h0buf, float* __restrict__ h1buf, float* __restrict__ hcbuf,
                 float* __restrict__ out,
                 const float* __restrict__ Whh0, const float* __restrict__ bhh0,
                 const float* __restrict__ Wih1, const float* __restrict__ Whh1,
                 const float* __restrict__ bih1, const float* __restrict__ bhh1,
                 const float* __restrict__ cWih, const float* __restrict__ cWhh,
                 const float* __restrict__ cb, int s) {
  __shared__ PipeSmem S;
  int blk = blockIdx.x;

  if (blk < 256) {                       // ---------- GRU0, t = s ----------
    if (s >= TT) return;
    int b0 = (blk >> 4) << 5;
    int c0 = (blk & 15) << 5;
    int cvalid = REC - c0; if (cvalid > 32) cvalid = 32;
    const float* hprev = h0buf + (size_t)((s+1)&1)*Bsz*REC;
    float*       hnew  = h0buf + (size_t)(s&1)*Bsz*REC;
    float ar[4][4]={{0}}, az[4][4]={{0}}, an[4][4]={{0}};
    gemm_segment(S.t, hprev, Whh0, b0, c0, cvalid, ar, az, an);
    int tx = threadIdx.x & 7, ty = threadIdx.x >> 3;
    #pragma unroll
    for (int i = 0; i < 4; ++i) {
      int b = b0 + ty*4 + i;
      const float* xgrow = xg0   + (size_t)b*G3;
      const float* hprow = hprev + (size_t)b*REC;
      float*       hnrow = hnew  + (size_t)b*REC;
      #pragma unroll
      for (int j = 0; j < 4; ++j) {
        int cl = tx*4 + j;
        if (cl >= cvalid) continue;
        int c = c0 + cl;
        float r = sigmoidf_(xgrow[c]       + ar[i][j] + bhh0[c]);
        float z = sigmoidf_(xgrow[REC+c]   + az[i][j] + bhh0[REC+c]);
        float n = tanhf   (xgrow[2*REC+c] + r*(an[i][j] + bhh0[2*REC+c]));
        hnrow[c] = (1.f - z)*n + z*hprow[c];
      }
    }
  } else if (blk < 512) {                // ---------- GRU1, t = s-1 ----------
    int t1 = s - 1;
    if (t1 < 0 || t1 >= TT) return;
    int bidx = blk - 256;
    int b0 = (bidx >> 4) << 5;
    int c0 = (bidx & 15) << 5;
    int cvalid = REC - c0; if (cvalid > 32) cvalid = 32;
    const float* x     = h0buf + (size_t)(t1&1)*Bsz*REC;       // GRU0 output at t1
    const float* hprev = h1buf + (size_t)((t1+1)&1)*Bsz*REC;
    float*       hnew  = h1buf + (size_t)(t1&1)*Bsz*REC;
    float ar[4][4]={{0}}, az[4][4]={{0}}, axn[4][4]={{0}}, ahn[4][4]={{0}};
    gemm_segment(S.t, x,     Wih1, b0, c0, cvalid, ar, az, axn);
    gemm_segment(S.t, hprev, Whh1, b0, c0, cvalid, ar, az, ahn);
    int tx = threadIdx.x & 7, ty = threadIdx.x >> 3;
    #pragma unroll
    for (int i = 0; i < 4; ++i) {
      int b = b0 + ty*4 + i;
      const float* hprow = hprev + (size_t)b*REC;
      float*       hnrow = hnew  + (size_t)b*REC;
      #pragma unroll
      for (int j = 0; j < 4; ++j) {
        int cl = tx*4 + j;
        if (cl >= cvalid) continue;
        int c = c0 + cl;
        float r = sigmoidf_(ar[i][j]  + bih1[c]       + bhh1[c]);
        float z = sigmoidf_(az[i][j]  + bih1[REC+c]   + bhh1[REC+c]);
        float n = tanhf   (axn[i][j] + bih1[2*REC+c] + r*(ahn[i][j] + bhh1[2*REC+c]));
        hnrow[c] = (1.f - z)*n + z*hprow[c];
      }
    }
  } else {                               // ---------- custom cell, t = s-2 ----------
    int tc = s - 2;
    if (tc < 0) return;                  // s<=121 guarantees tc<=119
    int b = blk - 512;
    int lane = threadIdx.x;
    const float* x  = h1buf + (size_t)(tc&1)*Bsz*REC;          // GRU1 output at tc
    const float* hp = hcbuf + (size_t)((tc+1)&1)*Bsz*NC;
    float*       hn = hcbuf + (size_t)(tc&1)*Bsz*NC;
    for (int k = lane; k < REC; k += 64) S.c.xs[k] = x[(size_t)b*REC + k];
    if (lane < NC) S.c.hs[lane] = hp[(size_t)b*NC + lane];
    __syncthreads();
    float v = -1e30f, u = 0.f, hpc = 0.f;
    if (lane < NC) {
      int c = lane;
      const float4* wr4 = (const float4*)(cWih + (size_t)c*REC);
      const float4* wz4 = (const float4*)(cWih + (size_t)(NC  + c)*REC);
      const float4* wn4 = (const float4*)(cWih + (size_t)(2*NC + c)*REC);
      float xr=0.f, xz=0.f, xn=0.f;
      for (int k4 = 0; k4 < REC/4; ++k4) {
        float4 wa = wr4[k4], wb = wz4[k4], wc = wn4[k4];
        float x0=S.c.xs[4*k4], x1=S.c.xs[4*k4+1], x2=S.c.xs[4*k4+2], x3=S.c.xs[4*k4+3];
        xr += wa.x*x0 + wa.y*x1 + wa.z*x2 + wa.w*x3;
        xz += wb.x*x0 + wb.y*x1 + wb.z*x2 + wb.w*x3;
        xn += wc.x*x0 + wc.y*x1 + wc.z*x2 + wc.w*x3;
      }
      float hr=0.f, hz=0.f;
      for (int k = 0; k < NC; ++k) {
        float hv = S.c.hs[k];
        hr += hv * cWhh[(size_t)c*NC + k];
        hz += hv * cWhh[(size_t)(NC + c)*NC + k];
      }
      float r = sigmoidf_(xr + hr + cb[c]);
      u       = sigmoidf_(xz + hz + cb[NC + c]);
      hpc = S.c.hs[c];
      S.c.rh[c] = r * hpc;               // NOTE: reference is (r*h) @ Whh_n.T
      v = xn;
    }
    __syncthreads();
    if (lane < NC) {
      int c = lane;
      float hnn = 0.f;
      for (int k = 0; k < NC; ++k) hnn += S.c.rh[k] * cWhh[(size_t)(2*NC + c)*NC + k];
      v = v + hnn + cb[2*NC + c];
    }
    float m = v;
    #pragma unroll
    for (int o = 32; o > 0; o >>= 1) m = fmaxf(m, __shfl_xor(m, o));
    float e = (lane < NC) ? __expf(v - m) : 0.f;
    float ssum = e;
    #pragma unroll
    for (int o = 32; o > 0; o >>= 1) ssum += __shfl_xor(ssum, o);
    if (lane < NC) {
      float nsm = e / ssum;
      float h2 = (1.f - u)*nsm + u*hpc;
      hn[(size_t)b*NC + lane] = h2;
      out[((size_t)b*TT + tc)*NC + lane] = h2;
    }
  }
}

extern "C" void kernel_launch(void* const* d_in, const int* in_sizes, int n_in,
                              void* d_out, int out_size, void* d_ws, size_t ws_size,
                              hipStream_t stream) {
  const float* z_in  = (const float*)d_in[0];
  const float* W0    = (const float*)d_in[1];
  const float* b0    = (const float*)d_in[2];
  const float* g0    = (const float*)d_in[3];
  const float* beta0 = (const float*)d_in[4];
  const float* W1    = (const float*)d_in[5];
  const float* b1    = (const float*)d_in[6];
  const float* g1    = (const float*)d_in[7];
  const float* beta1 = (const float*)d_in[8];
  const float* Wih0  = (const float*)d_in[9];
  const float* Whh0  = (const float*)d_in[10];
  const float* bih0  = (const float*)d_in[11];
  const float* bhh0  = (const float*)d_in[12];
  const float* Wih1  = (const float*)d_in[13];
  const float* Whh1  = (const float*)d_in[14];
  const float* bih1  = (const float*)d_in[15];
  const float* bhh1  = (const float*)d_in[16];
  const float* cWih  = (const float*)d_in[17];
  const float* cWhh  = (const float*)d_in[18];
  const float* cbih  = (const float*)d_in[19];
  float* out = (float*)d_out;

  float* ws  = (float*)d_ws;
  float* z1  = ws;
  float* z2  = z1 + (size_t)Bsz*HID;
  float* xg0 = z2 + (size_t)Bsz*HID;
  float* h0  = xg0 + (size_t)Bsz*G3;
  float* h1  = h0 + 2*(size_t)Bsz*REC;
  float* hcb = h1 + 2*(size_t)Bsz*REC;
  size_t zero_floats = 2*(size_t)Bsz*REC * 2 + 2*(size_t)Bsz*NC;

  hipMemsetAsync(h0, 0, zero_floats * sizeof(float), stream);

  dense_bn_kernel<<<Bsz, 256, 0, stream>>>(z_in, W0, b0, g0, beta0, z1);
  dense_bn_kernel<<<Bsz, 256, 0, stream>>>(z1,   W1, b1, g1, beta1, z2);
  xg0_kernel     <<<Bsz, 256, 0, stream>>>(z2, Wih0, bih0, xg0);

  for (int s = 0; s < TT + 2; ++s) {
    pipe_kernel<<<1024, 64, 0, stream>>>(xg0, h0, h1, hcb, out,
                                         Whh0, bhh0, Wih1, Whh1, bih1, bhh1,
                                         cWih, cWhh, cbih, s);
  }
}

// Round 2
// 13156.741 us; speedup vs baseline: 1.8120x; 1.8120x over previous
//
#include <hip/hip_runtime.h>
#include <math.h>

#define Bsz 512
#define HID 196
#define REC 488
#define NC  35
#define TT  120
#define G3  (3*REC)   // 1464

#define KT   16
#define NT   31       // ceil(488/16)
#define AS   36       // A-tile LDS row stride (32 rows + pad)
#define WS   36       // W-tile LDS row stride (32 cols + pad)

// GEMM blocks: 256 threads, 32 rows x 32 cols x 3 gates, K=488, double-buffered.
struct GSmem   { float A[2][KT][AS]; float W[2][3][KT][WS]; };
struct CellSmem{ float xs[4][492]; float hs[4][40]; float rh[4][40]; };
union  PipeSmem{ GSmem g; CellSmem c; };

__device__ __forceinline__ float sigmoidf_(float x) { return 1.0f / (1.0f + __expf(-x)); }

// ---- phase A: z = bn(X @ W.T + bias, g, beta) ----
__global__ void dense_bn_kernel(const float* __restrict__ X, const float* __restrict__ W,
                                const float* __restrict__ bias, const float* __restrict__ g,
                                const float* __restrict__ beta, float* __restrict__ Y) {
  __shared__ float xs[HID];
  int b = blockIdx.x;
  for (int k = threadIdx.x; k < HID; k += blockDim.x) xs[k] = X[(size_t)b*HID + k];
  __syncthreads();
  int j = threadIdx.x;
  if (j < HID) {
    const float4* wr = (const float4*)(W + (size_t)j*HID);
    float acc = 0.f;
    #pragma unroll 7
    for (int k4 = 0; k4 < HID/4; ++k4) {
      float4 w4 = wr[k4];
      acc += xs[4*k4+0]*w4.x + xs[4*k4+1]*w4.y + xs[4*k4+2]*w4.z + xs[4*k4+3]*w4.w;
    }
    float v = (acc + bias[j]) * 0.9995003746f;   // 1/sqrt(1+1e-3)
    Y[(size_t)b*HID + j] = g[j]*v + beta[j];
  }
}

// ---- phase A: xg0 = z @ Wih0.T + bih0   (constant over all T) ----
__global__ void xg0_kernel(const float* __restrict__ Z, const float* __restrict__ Wih,
                           const float* __restrict__ bih, float* __restrict__ XG) {
  __shared__ float zs[HID];
  int b = blockIdx.x;
  for (int k = threadIdx.x; k < HID; k += blockDim.x) zs[k] = Z[(size_t)b*HID + k];
  __syncthreads();
  for (int c = threadIdx.x; c < G3; c += blockDim.x) {
    const float4* wr = (const float4*)(Wih + (size_t)c*HID);
    float acc = 0.f;
    for (int k4 = 0; k4 < HID/4; ++k4) {
      float4 w4 = wr[k4];
      acc += zs[4*k4+0]*w4.x + zs[4*k4+1]*w4.y + zs[4*k4+2]*w4.z + zs[4*k4+3]*w4.w;
    }
    XG[(size_t)b*G3 + c] = acc + bih[c];
  }
}

// ---- LDS tile loaders (transposed [k][row/col], zero-padded past K=488) ----
__device__ __forceinline__ void loadA32(float (&dst)[KT][AS], const float* __restrict__ A,
                                        int b0, int kk) {
  int t = threadIdx.x;
  if (t < 128) {
    int row  = t >> 2;            // 0..31
    int kloc = (t & 3) << 2;      // 0,4,8,12
    int kb   = kk + kloc;
    float4 v = make_float4(0.f,0.f,0.f,0.f);
    if (kb + 3 < REC) v = *(const float4*)(A + (size_t)(b0 + row)*REC + kb);
    dst[kloc+0][row]=v.x; dst[kloc+1][row]=v.y; dst[kloc+2][row]=v.z; dst[kloc+3][row]=v.w;
  }
}

__device__ __forceinline__ void loadW3(float (&dst)[3][KT][WS], const float* __restrict__ W,
                                       int c0, int cvalid, int kk) {
  int t = threadIdx.x;
  #pragma unroll
  for (int s = 0; s < 2; ++s) {
    int idx = t + (s << 8);
    if (idx < 384) {              // 3 gates * 32 cols * 4 k-quads
      int g    = idx >> 7;
      int rem  = idx & 127;
      int c    = rem >> 2;        // 0..31
      int kloc = (rem & 3) << 2;
      int kb   = kk + kloc;
      float4 v = make_float4(0.f,0.f,0.f,0.f);
      if (c < cvalid && kb + 3 < REC)
        v = *(const float4*)(W + (size_t)(g*REC + c0 + c)*REC + kb);
      dst[g][kloc+0][c]=v.x; dst[g][kloc+1][c]=v.y; dst[g][kloc+2][c]=v.z; dst[g][kloc+3][c]=v.w;
    }
  }
}

// 12 FMA / k-step per thread: 2 rows x 2 cols x 3 gates
__device__ __forceinline__ void mma3(const float (&A)[KT][AS], const float (&W)[3][KT][WS],
                                     float (&ar)[2][2], float (&az)[2][2], float (&an)[2][2]) {
  int tx = threadIdx.x & 15, ty = threadIdx.x >> 4;
  #pragma unroll
  for (int k = 0; k < KT; ++k) {
    float a0 = A[k][ty*2 + 0];
    float a1 = A[k][ty*2 + 1];
    float wr0 = W[0][k][tx*2], wr1 = W[0][k][tx*2+1];
    float wz0 = W[1][k][tx*2], wz1 = W[1][k][tx*2+1];
    float wn0 = W[2][k][tx*2], wn1 = W[2][k][tx*2+1];
    ar[0][0]=fmaf(a0,wr0,ar[0][0]); ar[0][1]=fmaf(a0,wr1,ar[0][1]);
    ar[1][0]=fmaf(a1,wr0,ar[1][0]); ar[1][1]=fmaf(a1,wr1,ar[1][1]);
    az[0][0]=fmaf(a0,wz0,az[0][0]); az[0][1]=fmaf(a0,wz1,az[0][1]);
    az[1][0]=fmaf(a1,wz0,az[1][0]); az[1][1]=fmaf(a1,wz1,az[1][1]);
    an[0][0]=fmaf(a0,wn0,an[0][0]); an[0][1]=fmaf(a0,wn1,an[0][1]);
    an[1][0]=fmaf(a1,wn0,an[1][0]); an[1][1]=fmaf(a1,wn1,an[1][1]);
  }
}

// one full K=488 pass of A[32 rows] @ {Wr,Wz,Wn}[32 cols].T, double-buffered
__device__ __forceinline__ void gemm3_pass(GSmem& S, const float* __restrict__ A,
                                           const float* __restrict__ W,
                                           int b0, int c0, int cvalid,
                                           float (&ar)[2][2], float (&az)[2][2], float (&an)[2][2]) {
  loadA32(S.A[0], A, b0, 0);
  loadW3 (S.W[0], W, c0, cvalid, 0);
  __syncthreads();
  for (int tl = 0; tl < NT; ++tl) {
    int cur = tl & 1, nxt = cur ^ 1;
    if (tl + 1 < NT) {
      loadA32(S.A[nxt], A, b0, (tl+1)*KT);
      loadW3 (S.W[nxt], W, c0, cvalid, (tl+1)*KT);
    }
    mma3(S.A[cur], S.W[cur], ar, az, an);
    __syncthreads();
  }
}

// ---- fused pipelined step kernel: G0(t=s) || G1(t=s-1) || cell(t=s-2) ----
// grid: [0,256) GRU0 (16 row-tiles x 16 col-tiles), [256,512) GRU1, [512,640) cell
__global__ __launch_bounds__(256)
void pipe_kernel(const float* __restrict__ xg0,
                 float* __restrict__ h0buf, float* __restrict__ h1buf, float* __restrict__ hcbuf,
                 float* __restrict__ out,
                 const float* __restrict__ Whh0, const float* __restrict__ bhh0,
                 const float* __restrict__ Wih1, const float* __restrict__ Whh1,
                 const float* __restrict__ bih1, const float* __restrict__ bhh1,
                 const float* __restrict__ cWih, const float* __restrict__ cWhh,
                 const float* __restrict__ cb, int s) {
  __shared__ PipeSmem S;
  int blk = blockIdx.x;

  if (blk < 256) {                       // ---------- GRU0, t = s ----------
    if (s >= TT) return;
    int rt = blk >> 4, ct = blk & 15;
    int b0 = rt << 5;
    int c0 = ct << 5;
    int cvalid = REC - c0; if (cvalid > 32) cvalid = 32;
    const float* hprev = h0buf + (size_t)((s+1)&1)*Bsz*REC;
    float*       hnew  = h0buf + (size_t)(s&1)*Bsz*REC;
    float ar[2][2]={{0}}, az[2][2]={{0}}, an[2][2]={{0}};
    gemm3_pass(S.g, hprev, Whh0, b0, c0, cvalid, ar, az, an);
    int tx = threadIdx.x & 15, ty = threadIdx.x >> 4;
    #pragma unroll
    for (int i = 0; i < 2; ++i) {
      int b = b0 + ty*2 + i;
      const float* xgrow = xg0   + (size_t)b*G3;
      const float* hprow = hprev + (size_t)b*REC;
      float*       hnrow = hnew  + (size_t)b*REC;
      #pragma unroll
      for (int j = 0; j < 2; ++j) {
        int cl = tx*2 + j;
        if (cl >= cvalid) continue;
        int c = c0 + cl;
        float r = sigmoidf_(xgrow[c]        + ar[i][j] + bhh0[c]);
        float z = sigmoidf_(xgrow[REC+c]    + az[i][j] + bhh0[REC+c]);
        float n = tanhf    (xgrow[2*REC+c]  + r*(an[i][j] + bhh0[2*REC+c]));
        hnrow[c] = (1.f - z)*n + z*hprow[c];
      }
    }
  } else if (blk < 512) {                // ---------- GRU1, t = s-1 ----------
    int t1 = s - 1;
    if (t1 < 0 || t1 >= TT) return;
    int bidx = blk - 256;
    int rt = bidx >> 4, ct = bidx & 15;
    int b0 = rt << 5;
    int c0 = ct << 5;
    int cvalid = REC - c0; if (cvalid > 32) cvalid = 32;
    const float* x     = h0buf + (size_t)(t1&1)*Bsz*REC;       // GRU0 output at t1
    const float* hprev = h1buf + (size_t)((t1+1)&1)*Bsz*REC;
    float*       hnew  = h1buf + (size_t)(t1&1)*Bsz*REC;
    float ar[2][2]={{0}}, az[2][2]={{0}}, axn[2][2]={{0}}, ahn[2][2]={{0}};
    gemm3_pass(S.g, x,     Wih1, b0, c0, cvalid, ar, az, axn);
    gemm3_pass(S.g, hprev, Whh1, b0, c0, cvalid, ar, az, ahn);
    int tx = threadIdx.x & 15, ty = threadIdx.x >> 4;
    #pragma unroll
    for (int i = 0; i < 2; ++i) {
      int b = b0 + ty*2 + i;
      const float* hprow = hprev + (size_t)b*REC;
      float*       hnrow = hnew  + (size_t)b*REC;
      #pragma unroll
      for (int j = 0; j < 2; ++j) {
        int cl = tx*2 + j;
        if (cl >= cvalid) continue;
        int c = c0 + cl;
        float r = sigmoidf_(ar[i][j]  + bih1[c]       + bhh1[c]);
        float z = sigmoidf_(az[i][j]  + bih1[REC+c]   + bhh1[REC+c]);
        float n = tanhf    (axn[i][j] + bih1[2*REC+c] + r*(ahn[i][j] + bhh1[2*REC+c]));
        hnrow[c] = (1.f - z)*n + z*hprow[c];
      }
    }
  } else {                               // ---------- custom cell, t = s-2 ----------
    int tc = s - 2;
    if (tc < 0) return;
    int ci = blk - 512;                  // 0..127, 4 batch items per block (1/wave)
    int wave = threadIdx.x >> 6;
    int lane = threadIdx.x & 63;
    int b = ci*4 + wave;
    const float* x  = h1buf + (size_t)(tc&1)*Bsz*REC;          // GRU1 output at tc
    const float* hp = hcbuf + (size_t)((tc+1)&1)*Bsz*NC;
    float*       hn = hcbuf + (size_t)(tc&1)*Bsz*NC;
    float* xs = S.c.xs[wave];
    float* hs = S.c.hs[wave];
    float* rh = S.c.rh[wave];
    for (int k = lane; k < REC; k += 64) xs[k] = x[(size_t)b*REC + k];
    if (lane < NC) hs[lane] = hp[(size_t)b*NC + lane];
    __syncthreads();
    float v = -1e30f, u = 0.f, hpc = 0.f;
    if (lane < NC) {
      int c = lane;
      const float4* wr4 = (const float4*)(cWih + (size_t)c*REC);
      const float4* wz4 = (const float4*)(cWih + (size_t)(NC  + c)*REC);
      const float4* wn4 = (const float4*)(cWih + (size_t)(2*NC + c)*REC);
      float xr=0.f, xz=0.f, xn=0.f;
      #pragma unroll 2
      for (int k4 = 0; k4 < REC/4; ++k4) {
        float4 wa = wr4[k4], wb = wz4[k4], wc = wn4[k4];
        float x0=xs[4*k4], x1=xs[4*k4+1], x2=xs[4*k4+2], x3=xs[4*k4+3];
        xr += wa.x*x0 + wa.y*x1 + wa.z*x2 + wa.w*x3;
        xz += wb.x*x0 + wb.y*x1 + wb.z*x2 + wb.w*x3;
        xn += wc.x*x0 + wc.y*x1 + wc.z*x2 + wc.w*x3;
      }
      float hr=0.f, hz=0.f;
      for (int k = 0; k < NC; ++k) {
        float hv = hs[k];
        hr += hv * cWhh[(size_t)c*NC + k];
        hz += hv * cWhh[(size_t)(NC + c)*NC + k];
      }
      float r = sigmoidf_(xr + hr + cb[c]);
      u       = sigmoidf_(xz + hz + cb[NC + c]);
      hpc = hs[c];
      rh[c] = r * hpc;                   // reference: (r*h) @ Whh_n.T
      v = xn;
    }
    __syncthreads();
    if (lane < NC) {
      int c = lane;
      float hnn = 0.f;
      for (int k = 0; k < NC; ++k) hnn += rh[k] * cWhh[(size_t)(2*NC + c)*NC + k];
      v = v + hnn + cb[2*NC + c];
    }
    float m = v;
    #pragma unroll
    for (int o = 32; o > 0; o >>= 1) m = fmaxf(m, __shfl_xor(m, o));
    float e = (lane < NC) ? __expf(v - m) : 0.f;
    float ssum = e;
    #pragma unroll
    for (int o = 32; o > 0; o >>= 1) ssum += __shfl_xor(ssum, o);
    if (lane < NC) {
      float nsm = e / ssum;
      float h2 = (1.f - u)*nsm + u*hpc;
      hn[(size_t)b*NC + lane] = h2;
      out[((size_t)b*TT + tc)*NC + lane] = h2;
    }
  }
}

extern "C" void kernel_launch(void* const* d_in, const int* in_sizes, int n_in,
                              void* d_out, int out_size, void* d_ws, size_t ws_size,
                              hipStream_t stream) {
  const float* z_in  = (const float*)d_in[0];
  const float* W0    = (const float*)d_in[1];
  const float* b0    = (const float*)d_in[2];
  const float* g0    = (const float*)d_in[3];
  const float* beta0 = (const float*)d_in[4];
  const float* W1    = (const float*)d_in[5];
  const float* b1    = (const float*)d_in[6];
  const float* g1    = (const float*)d_in[7];
  const float* beta1 = (const float*)d_in[8];
  const float* Wih0  = (const float*)d_in[9];
  const float* Whh0  = (const float*)d_in[10];
  const float* bih0  = (const float*)d_in[11];
  const float* bhh0  = (const float*)d_in[12];
  const float* Wih1  = (const float*)d_in[13];
  const float* Whh1  = (const float*)d_in[14];
  const float* bih1  = (const float*)d_in[15];
  const float* bhh1  = (const float*)d_in[16];
  const float* cWih  = (const float*)d_in[17];
  const float* cWhh  = (const float*)d_in[18];
  const float* cbih  = (const float*)d_in[19];
  float* out = (float*)d_out;

  float* ws  = (float*)d_ws;
  float* z1  = ws;
  float* z2  = z1 + (size_t)Bsz*HID;
  float* xg0 = z2 + (size_t)Bsz*HID;
  float* h0  = xg0 + (size_t)Bsz*G3;
  float* h1  = h0 + 2*(size_t)Bsz*REC;
  float* hcb = h1 + 2*(size_t)Bsz*REC;
  size_t zero_floats = 2*(size_t)Bsz*REC * 2 + 2*(size_t)Bsz*NC;

  hipMemsetAsync(h0, 0, zero_floats * sizeof(float), stream);

  dense_bn_kernel<<<Bsz, 256, 0, stream>>>(z_in, W0, b0, g0, beta0, z1);
  dense_bn_kernel<<<Bsz, 256, 0, stream>>>(z1,   W1, b1, g1, beta1, z2);
  xg0_kernel     <<<Bsz, 256, 0, stream>>>(z2, Wih0, bih0, xg0);

  for (int s = 0; s < TT + 2; ++s) {
    pipe_kernel<<<640, 256, 0, stream>>>(xg0, h0, h1, hcb, out,
                                         Whh0, bhh0, Wih1, Whh1, bih1, bhh1,
                                         cWih, cWhh, cbih, s);
  }
}